// Round 6
// baseline (190.934 us; speedup 1.0000x reference)
//
#include <hip/hip_runtime.h>
#include <hip/hip_bf16.h>
#include <math.h>

#define BB 64
#define QQ 900
#define GG 100
#define NCLS 10
#define CP1 11

#define STRIDE 960   // 64*15: every lane owns exactly KPL columns; cols 900..959 are +inf pads
#define KPL 15
#define NT 512
#define NW 8
#define QMASK 255    // ring queue; live entries <= n <= 100 < 256
#define ROUND_CAP 20000

#define CLS_W 2.0f
#define L1_W 5.0f
#define GIOU_W 2.0f

struct Accum {
  double wnll, wt, l1, gl;
  int nm, counter;
  int pad[6];
};

// One block per batch: cost-tile gen -> rowmin -> greedy -> single-wave f32 ARR -> fused loss.
__global__ __launch_bounds__(NT) void fused_kernel(
    const float* __restrict__ logits, const float* __restrict__ pboxes,
    const int* __restrict__ gcls, const float* __restrict__ gboxes,
    float* __restrict__ costws, Accum* acc, float* out) {
  const int b = blockIdx.x;
  const int tid = threadIdx.x;
  const int lane = tid & 63;
  const int w = tid >> 6;

  __shared__ float s_prob[NT * 13];     // softmax probs, stride 13 (bank-conflict-free)
  __shared__ float s_gb[GG * 4];
  __shared__ int   s_gc[GG];
  __shared__ float vl[STRIDE + 2];      // column duals (f32), <= 0
  __shared__ int   p[QQ + 1];           // column -> owning row (1-based), 0 = free
  __shared__ int   way[STRIDE + 2];     // greedy claim scratch
  __shared__ float m1l[GG + 1], m2l[GG + 1];
  __shared__ int   aminl[GG + 1];
  __shared__ int   queue[QMASK + 1];
  __shared__ int   sh_n, sh_qtail;
  __shared__ double r0[NW], r1[NW], r2[NW], r3[NW];
  __shared__ int r4[NW];

  if (tid == 0) { sh_n = 0; sh_qtail = 0; }
  for (int j = tid; j <= QQ; j += NT) p[j] = 0;
  for (int j = tid; j < STRIDE + 2; j += NT) { vl[j] = 0.f; way[j] = 0x7FFFFFFF; }
  if (tid < GG) s_gc[tid] = gcls[b * GG + tid];
  for (int i = tid; i < GG * 4; i += NT) s_gb[i] = gboxes[b * GG * 4 + i];
  __syncthreads();
  if (tid < GG && s_gc[tid] >= 0) atomicAdd(&sh_n, 1);
  __syncthreads();
  const int n = sh_n;
  float* Cb = costws + (size_t)b * GG * STRIDE;

  // ---- Phase A: cost rows [0,n) for this batch (parallel over queries) ----
  for (int q = tid; q < QQ; q += NT) {
    const float* lg = logits + ((size_t)b * QQ + q) * CP1;
    float l[CP1];
    float mx = -1e30f;
    for (int c = 0; c < CP1; ++c) { l[c] = lg[c]; mx = fmaxf(mx, l[c]); }
    float se = 0.f;
    for (int c = 0; c < CP1; ++c) { l[c] = expf(l[c] - mx); se += l[c]; }
    const float inv = 1.0f / se;
    for (int c = 0; c < CP1; ++c) s_prob[tid * 13 + c] = l[c] * inv;
    const float* pb = pboxes + ((size_t)b * QQ + q) * 4;
    const float pcx = pb[0], pcy = pb[1], pw = pb[2], ph = pb[3];
    const float px1 = pcx - 0.5f * pw, py1 = pcy - 0.5f * ph;
    const float px2 = pcx + 0.5f * pw, py2 = pcy + 0.5f * ph;
    const float pa = fmaxf(px2 - px1, 0.f) * fmaxf(py2 - py1, 0.f);
    for (int g = 0; g < n; ++g) {
      int cls = s_gc[g];
      cls = cls < 0 ? 0 : (cls > NCLS - 1 ? NCLS - 1 : cls);
      const float cc = -s_prob[tid * 13 + cls];
      const float gcx = s_gb[g * 4 + 0], gcy = s_gb[g * 4 + 1];
      const float gw  = s_gb[g * 4 + 2], gh  = s_gb[g * 4 + 3];
      const float l1 = fabsf(pcx - gcx) + fabsf(pcy - gcy) + fabsf(pw - gw) + fabsf(ph - gh);
      const float gx1 = gcx - 0.5f * gw, gy1 = gcy - 0.5f * gh;
      const float gx2 = gcx + 0.5f * gw, gy2 = gcy + 0.5f * gh;
      const float ga = fmaxf(gx2 - gx1, 0.f) * fmaxf(gy2 - gy1, 0.f);
      const float ltx = fmaxf(px1, gx1), lty = fmaxf(py1, gy1);
      const float rbx = fminf(px2, gx2), rby = fminf(py2, gy2);
      const float iw = fmaxf(rbx - ltx, 0.f), ih = fmaxf(rby - lty, 0.f);
      const float inter = iw * ih;
      const float uni = pa + ga - inter;
      const float iou = inter / fmaxf(uni, 1e-6f);
      const float ex1 = fminf(px1, gx1), ey1 = fminf(py1, gy1);
      const float ex2 = fmaxf(px2, gx2), ey2 = fmaxf(py2, gy2);
      const float ew = fmaxf(ex2 - ex1, 0.f), eh = fmaxf(ey2 - ey1, 0.f);
      const float enc = ew * eh;
      const float giou = iou - (enc - uni) / fmaxf(enc, 1e-6f);
      Cb[(size_t)g * STRIDE + q] = CLS_W * cc + L1_W * l1 - GIOU_W * giou;
    }
  }
  {  // pad columns 900..959: never selectable
    const int npad = n * (STRIDE - QQ);
    for (int x = tid; x < npad; x += NT) {
      const int g = x / (STRIDE - QQ);
      const int c = QQ + (x - g * (STRIDE - QQ));
      Cb[(size_t)g * STRIDE + c] = 1e30f;
    }
  }
  __threadfence_block();
  __syncthreads();

  // ---- Phase B: per-row (min1, min2, argmin), 8 waves in parallel, f32 ----
  for (int r = w; r < n; r += NW) {
    const float* Cr = Cb + (size_t)r * STRIDE + lane;
    float m1 = 3e38f, m2 = 3e38f;
    int j1 = 0x7FFFFFFF;
#pragma unroll
    for (int k = 0; k < KPL; ++k) {
      const float c = Cr[k << 6];
      const int idx = 1 + lane + (k << 6);
      if (c < m1) { m2 = m1; m1 = c; j1 = idx; }
      else if (c < m2) m2 = c;
    }
    for (int m = 1; m < 64; m <<= 1) {
      const float o1 = __shfl_xor(m1, m);
      const float o2 = __shfl_xor(m2, m);
      const int oj = __shfl_xor(j1, m);
      if (o1 < m1) { m2 = fminf(m1, o2); m1 = o1; j1 = oj; }
      else m2 = fminf(m2, o1);
    }
    if (lane == 0) { m1l[r] = m1; m2l[r] = m2; aminl[r] = j1; }
  }
  __syncthreads();

  // ---- Phase C: parallel greedy claim (valid ARR steps at v == 0) ----
  if (tid < n) atomicMin(&way[aminl[tid]], tid);
  __syncthreads();
  if (tid < n) {
    const int j1 = aminl[tid];
    if (way[j1] == tid) {  // winner: claim; dual update vl[j1] = m1 - m2 (<= 0)
      p[j1] = tid + 1;
      vl[j1] = m1l[tid] - m2l[tid];
    } else {               // loser: queue for ARR
      const int t0 = atomicAdd(&sh_qtail, 1);
      queue[t0 & QMASK] = tid + 1;
    }
  }
  __syncthreads();

  // ---- Phase D: single-wave ARR, duals in registers, f32 ----
  if (w == 0) {
    float v[KPL], rc[KPL];
#pragma unroll
    for (int k = 0; k < KPL; ++k) v[k] = vl[1 + lane + (k << 6)];
    int head = 0, tail = sh_qtail, rounds = 0;
    int cur = -1;
    if (head < tail) {
      cur = queue[head & QMASK];
      const float* Cr = Cb + (size_t)(cur - 1) * STRIDE + lane;
#pragma unroll
      for (int k = 0; k < KPL; ++k) rc[k] = Cr[k << 6];
    }
    while (head < tail && rounds < ROUND_CAP) {
      const int i = cur;
      head++;
      // scan all 960 columns: reduced cost = rc - v
      float m1 = 3e38f, m2 = 3e38f;
      int j1 = 0x7FFFFFFF;
#pragma unroll
      for (int k = 0; k < KPL; ++k) {
        const float c = rc[k] - v[k];
        const int idx = 1 + lane + (k << 6);
        if (c < m1) { m2 = m1; m1 = c; j1 = idx; }
        else if (c < m2) m2 = c;
      }
      for (int m = 1; m < 64; m <<= 1) {
        const float o1 = __shfl_xor(m1, m);
        const float o2 = __shfl_xor(m2, m);
        const int oj = __shfl_xor(j1, m);
        if (o1 < m1) { m2 = fminf(m1, o2); m1 = o1; j1 = oj; }
        else m2 = fminf(m2, o1);
      }
      float d = m2 - m1;
      if (!(d > 1e-7f)) d = 1e-7f;   // forced progress on ties
      const int c0 = j1 - 1;
      if ((c0 & 63) == lane) v[c0 >> 6] -= d;
      const int k0 = p[j1];          // broadcast LDS read
      p[j1] = i;                     // same-addr same-val write, one lane wins
      if (k0 > 0) {
        if (lane == 0) queue[tail & QMASK] = k0;
        tail++;
      }
      cur = -1;
      if (head < tail) {             // prefetch next pop (FIFO order is known)
        cur = queue[head & QMASK];
        const float* Cr = Cb + (size_t)(cur - 1) * STRIDE + lane;
#pragma unroll
        for (int k = 0; k < KPL; ++k) rc[k] = Cr[k << 6];
      }
      rounds++;
    }
    // cap leftovers stay unmatched: graceful ~2e-3 loss shift (expected: never)
  }
  __syncthreads();

  // ---- Phase E: fused loss over this batch's 900 queries (512 threads) ----
  double wnll = 0.0, wt = 0.0, l1d = 0.0, gld = 0.0;
  int nm = 0;
  for (int q = tid; q < QQ; q += NT) {
    const int idx = b * QQ + q;
    const float* lg = logits + (size_t)idx * CP1;
    float l[CP1];
    float mx = -1e30f;
    for (int c = 0; c < CP1; ++c) { l[c] = lg[c]; mx = fmaxf(mx, l[c]); }
    float se = 0.f;
    for (int c = 0; c < CP1; ++c) se += expf(l[c] - mx);
    const float lse = logf(se);
    const int g = p[q + 1] - 1;   // row -> gt index (valid gts are a prefix)
    const int t = (g >= 0) ? s_gc[g] : NCLS;
    float lt = l[0];
    for (int c = 1; c < CP1; ++c) lt = (c == t) ? l[c] : lt;
    const float logp = (lt - mx) - lse;
    const float wgt = (t == NCLS) ? 0.1f : 1.0f;
    wnll += (double)(wgt * (-logp));
    wt += (double)wgt;
    if (g >= 0) {
      nm += 1;
      const float* pb = pboxes + (size_t)idx * 4;
      const float* gb = &s_gb[g * 4];
      const float pcx = pb[0], pcy = pb[1], pw = pb[2], ph = pb[3];
      const float gcx = gb[0], gcy = gb[1], gw = gb[2], gh = gb[3];
      const float l1 = fabsf(pcx - gcx) + fabsf(pcy - gcy) + fabsf(pw - gw) + fabsf(ph - gh);
      const float px1 = pcx - 0.5f * pw, py1 = pcy - 0.5f * ph;
      const float px2 = pcx + 0.5f * pw, py2 = pcy + 0.5f * ph;
      const float gx1 = gcx - 0.5f * gw, gy1 = gcy - 0.5f * gh;
      const float gx2 = gcx + 0.5f * gw, gy2 = gcy + 0.5f * gh;
      const float pa = fmaxf(px2 - px1, 0.f) * fmaxf(py2 - py1, 0.f);
      const float ga = fmaxf(gx2 - gx1, 0.f) * fmaxf(gy2 - gy1, 0.f);
      const float ltx = fmaxf(px1, gx1), lty = fmaxf(py1, gy1);
      const float rbx = fminf(px2, gx2), rby = fminf(py2, gy2);
      const float iw = fmaxf(rbx - ltx, 0.f), ih = fmaxf(rby - lty, 0.f);
      const float inter = iw * ih;
      const float uni = pa + ga - inter;
      const float iou = inter / fmaxf(uni, 1e-6f);
      const float ex1 = fminf(px1, gx1), ey1 = fminf(py1, gy1);
      const float ex2 = fmaxf(px2, gx2), ey2 = fmaxf(py2, gy2);
      const float ew = fmaxf(ex2 - ex1, 0.f), eh = fmaxf(ey2 - ey1, 0.f);
      const float enc = ew * eh;
      const float giou = iou - (enc - uni) / fmaxf(enc, 1e-6f);
      l1d += (double)l1;
      gld += (double)(1.0f - giou);
    }
  }

  for (int off = 32; off; off >>= 1) {
    wnll += __shfl_down(wnll, off);
    wt   += __shfl_down(wt, off);
    l1d  += __shfl_down(l1d, off);
    gld  += __shfl_down(gld, off);
    nm   += __shfl_down(nm, off);
  }
  if (lane == 0) { r0[w] = wnll; r1[w] = wt; r2[w] = l1d; r3[w] = gld; r4[w] = nm; }
  __syncthreads();
  if (tid == 0) {
    for (int x = 1; x < NW; ++x) { wnll += r0[x]; wt += r1[x]; l1d += r2[x]; gld += r3[x]; nm += r4[x]; }
    atomicAdd(&acc->wnll, wnll);
    atomicAdd(&acc->wt, wt);
    atomicAdd(&acc->l1, l1d);
    atomicAdd(&acc->gl, gld);
    atomicAdd(&acc->nm, nm);
    __threadfence();
    const int ticket = atomicAdd(&acc->counter, 1);
    if (ticket == BB - 1) {
      const double fw = atomicAdd(&acc->wnll, 0.0);
      const double fwt = atomicAdd(&acc->wt, 0.0);
      const double fl1 = atomicAdd(&acc->l1, 0.0);
      const double fgl = atomicAdd(&acc->gl, 0.0);
      int fnm = atomicAdd(&acc->nm, 0);
      if (fnm < 1) fnm = 1;
      const double loss = (double)CLS_W * (fw / fwt) +
                          ((double)L1_W * fl1 + (double)GIOU_W * fgl) / (double)fnm;
      out[0] = (float)loss;
    }
  }
}

extern "C" void kernel_launch(void* const* d_in, const int* in_sizes, int n_in,
                              void* d_out, int out_size, void* d_ws, size_t ws_size,
                              hipStream_t stream) {
  const float* logits = (const float*)d_in[0];
  const float* pboxes = (const float*)d_in[1];
  const int*   gcls   = (const int*)d_in[2];
  const float* gboxes = (const float*)d_in[3];

  char* ws = (char*)d_ws;
  Accum* acc = (Accum*)ws;                 // 64 B, zeroed below
  float* cost = (float*)(ws + 128);        // B*G*960 floats ~ 24.6 MB

  hipMemsetAsync(acc, 0, sizeof(Accum), stream);
  fused_kernel<<<BB, NT, 0, stream>>>(logits, pboxes, gcls, gboxes, cost, acc, (float*)d_out);
}

// Round 7
// 123.721 us; speedup vs baseline: 1.5433x; 1.5433x over previous
//
#include <hip/hip_runtime.h>
#include <hip/hip_bf16.h>
#include <math.h>

#define BB 64
#define QQ 900
#define GG 100
#define NCLS 10
#define CP1 11

#define STRIDE 960   // 64*15: every lane owns exactly KPL columns; cols 900..959 are +inf pads
#define KPL 15
#define NT 512
#define NW 8
#define QMASK 255    // ring queue; live entries <= n <= 100 < 256
#define ROUND_CAP 20000

#define CLS_W 2.0f
#define L1_W 5.0f
#define GIOU_W 2.0f

struct Accum {
  double wnll, wt, l1, gl;
  int nm, counter;
  int pad[6];
};

// ---------------- cost matrix: cost[b][g][q], 256 blocks (full-chip parallel) ----------------
__global__ __launch_bounds__(256) void cost_kernel(
    const float* __restrict__ logits, const float* __restrict__ pboxes,
    const int* __restrict__ gcls, const float* __restrict__ gboxes,
    float* __restrict__ cost, Accum* acc) {
  const int b = blockIdx.y;
  const int q = blockIdx.x * 256 + threadIdx.x;

  if (blockIdx.x == 0 && blockIdx.y == 0 && threadIdx.x == 0) {
    acc->wnll = 0.0; acc->wt = 0.0; acc->l1 = 0.0; acc->gl = 0.0;
    acc->nm = 0; acc->counter = 0;
  }

  __shared__ float s_gb[GG * 4];
  __shared__ int   s_gc[GG];
  __shared__ float s_prob[256 * 13];

  for (int i = threadIdx.x; i < GG * 4; i += 256) s_gb[i] = gboxes[b * GG * 4 + i];
  for (int i = threadIdx.x; i < GG; i += 256)     s_gc[i] = gcls[b * GG + i];

  float pcx = 0.f, pcy = 0.f, pw = 0.f, ph = 0.f;
  if (q < QQ) {
    const float* lg = logits + ((size_t)b * QQ + q) * CP1;
    float l[CP1];
    float mx = -1e30f;
    for (int c = 0; c < CP1; ++c) { l[c] = lg[c]; mx = fmaxf(mx, l[c]); }
    float se = 0.f;
    for (int c = 0; c < CP1; ++c) { l[c] = expf(l[c] - mx); se += l[c]; }
    float inv = 1.0f / se;
    for (int c = 0; c < CP1; ++c) s_prob[threadIdx.x * 13 + c] = l[c] * inv;
    const float* pb = pboxes + ((size_t)b * QQ + q) * 4;
    pcx = pb[0]; pcy = pb[1]; pw = pb[2]; ph = pb[3];
  }
  __syncthreads();
  if (q >= STRIDE) return;

  float* crow = cost + ((size_t)b * GG) * STRIDE + q;
  if (q >= QQ) {  // pad columns: huge cost, never selected
    for (int g = 0; g < GG; ++g) crow[(size_t)g * STRIDE] = 1e30f;
    return;
  }

  const float px1 = pcx - 0.5f * pw, py1 = pcy - 0.5f * ph;
  const float px2 = pcx + 0.5f * pw, py2 = pcy + 0.5f * ph;
  const float pa = fmaxf(px2 - px1, 0.f) * fmaxf(py2 - py1, 0.f);

  for (int g = 0; g < GG; ++g) {
    int cls = s_gc[g];
    cls = cls < 0 ? 0 : (cls > NCLS - 1 ? NCLS - 1 : cls);
    const float cc = -s_prob[threadIdx.x * 13 + cls];
    const float gcx = s_gb[g * 4 + 0], gcy = s_gb[g * 4 + 1];
    const float gw  = s_gb[g * 4 + 2], gh  = s_gb[g * 4 + 3];
    const float l1 = fabsf(pcx - gcx) + fabsf(pcy - gcy) + fabsf(pw - gw) + fabsf(ph - gh);
    const float gx1 = gcx - 0.5f * gw, gy1 = gcy - 0.5f * gh;
    const float gx2 = gcx + 0.5f * gw, gy2 = gcy + 0.5f * gh;
    const float ga = fmaxf(gx2 - gx1, 0.f) * fmaxf(gy2 - gy1, 0.f);
    const float ltx = fmaxf(px1, gx1), lty = fmaxf(py1, gy1);
    const float rbx = fminf(px2, gx2), rby = fminf(py2, gy2);
    const float iw = fmaxf(rbx - ltx, 0.f), ih = fmaxf(rby - lty, 0.f);
    const float inter = iw * ih;
    const float uni = pa + ga - inter;
    const float iou = inter / fmaxf(uni, 1e-6f);
    const float ex1 = fminf(px1, gx1), ey1 = fminf(py1, gy1);
    const float ex2 = fmaxf(px2, gx2), ey2 = fmaxf(py2, gy2);
    const float ew = fmaxf(ex2 - ex1, 0.f), eh = fmaxf(ey2 - ey1, 0.f);
    const float enc = ew * eh;
    const float giou = iou - (enc - uni) / fmaxf(enc, 1e-6f);
    crow[(size_t)g * STRIDE] = CLS_W * cc + L1_W * l1 - GIOU_W * giou;
  }
}

// ---------------- jv: rowmin (8-wave) + greedy + single-wave f32 ARR + fused loss ----------------
__global__ __launch_bounds__(NT) void jv_kernel(
    const float* __restrict__ logits, const float* __restrict__ pboxes,
    const int* __restrict__ gcls, const float* __restrict__ gboxes,
    const float* __restrict__ cost, Accum* acc, float* out) {
  const int b = blockIdx.x;
  const int tid = threadIdx.x;
  const int lane = tid & 63;
  const int w = tid >> 6;

  __shared__ float vl[STRIDE + 2];      // column duals (f32), <= 0
  __shared__ int   p[QQ + 1];           // column -> owning row (1-based), 0 = free
  __shared__ int   way[STRIDE + 2];     // greedy claim scratch
  __shared__ float m1l[GG + 1], m2l[GG + 1];
  __shared__ int   aminl[GG + 1];
  __shared__ int   s_gc[GG];
  __shared__ int   queue[QMASK + 1];
  __shared__ int   sh_n, sh_qtail;
  __shared__ double r0[NW], r1[NW], r2[NW], r3[NW];
  __shared__ int r4[NW];

  if (tid == 0) { sh_n = 0; sh_qtail = 0; }
  for (int j = tid; j <= QQ; j += NT) p[j] = 0;
  for (int j = tid; j < STRIDE + 2; j += NT) { vl[j] = 0.f; way[j] = 0x7FFFFFFF; }
  if (tid < GG) s_gc[tid] = gcls[b * GG + tid];
  __syncthreads();
  if (tid < GG && s_gc[tid] >= 0) atomicAdd(&sh_n, 1);
  __syncthreads();
  const int n = sh_n;
  const float* Cb = cost + (size_t)b * GG * STRIDE;

  // ---- Phase B: per-row (min1, min2, argmin), 8 waves in parallel, f32, 2-chain ILP ----
  for (int r = w; r < n; r += NW) {
    const float* Cr = Cb + (size_t)r * STRIDE + lane;
    float rca[KPL];
#pragma unroll
    for (int k = 0; k < KPL; ++k) rca[k] = Cr[k << 6];
    float m1 = 3e38f, m2 = 3e38f, n1 = 3e38f, n2 = 3e38f;
    int j1 = 0x7FFFFFFF, i1 = 0x7FFFFFFF;
#pragma unroll
    for (int k = 0; k < 8; ++k) {
      const float c = rca[k];
      if (c < m1) { m2 = m1; m1 = c; j1 = 1 + lane + (k << 6); }
      else if (c < m2) m2 = c;
    }
#pragma unroll
    for (int k = 8; k < KPL; ++k) {
      const float c = rca[k];
      if (c < n1) { n2 = n1; n1 = c; i1 = 1 + lane + (k << 6); }
      else if (c < n2) n2 = c;
    }
    if (n1 < m1) { m2 = fminf(m1, n2); m1 = n1; j1 = i1; }
    else m2 = fminf(m2, n1);
    for (int m = 1; m < 64; m <<= 1) {
      const float o1 = __shfl_xor(m1, m);
      const float o2 = __shfl_xor(m2, m);
      const int oj = __shfl_xor(j1, m);
      if (o1 < m1) { m2 = fminf(m1, o2); m1 = o1; j1 = oj; }
      else m2 = fminf(m2, o1);
    }
    if (lane == 0) { m1l[r] = m1; m2l[r] = m2; aminl[r] = j1; }
  }
  __syncthreads();

  // ---- Phase C: parallel greedy claim (valid ARR steps at v == 0) ----
  if (tid < n) atomicMin(&way[aminl[tid]], tid);
  __syncthreads();
  if (tid < n) {
    const int j1 = aminl[tid];
    if (way[j1] == tid) {  // winner: claim; dual update vl[j1] = m1 - m2 (<= 0)
      p[j1] = tid + 1;
      vl[j1] = m1l[tid] - m2l[tid];
    } else {               // loser: queue for ARR
      const int t0 = atomicAdd(&sh_qtail, 1);
      queue[t0 & QMASK] = tid + 1;
    }
  }
  __syncthreads();

  // ---- Phase D: single-wave ARR, duals in registers, f32, strict progress ----
  if (w == 0) {
    float v[KPL], rc[KPL];
#pragma unroll
    for (int k = 0; k < KPL; ++k) v[k] = vl[1 + lane + (k << 6)];
    int head = 0, tail = sh_qtail, rounds = 0;
    int cur = -1;
    if (head < tail) {
      cur = queue[head & QMASK];
      const float* Cr = Cb + (size_t)(cur - 1) * STRIDE + lane;
#pragma unroll
      for (int k = 0; k < KPL; ++k) rc[k] = Cr[k << 6];
    }
    while (head < tail && rounds < ROUND_CAP) {
      const int i = cur;
      head++;
      // scan 960 reduced costs: two independent chains + merge (ILP)
      float m1 = 3e38f, m2 = 3e38f, n1 = 3e38f, n2 = 3e38f;
      int j1 = 0x7FFFFFFF, i1 = 0x7FFFFFFF;
#pragma unroll
      for (int k = 0; k < 8; ++k) {
        const float c = rc[k] - v[k];
        if (c < m1) { m2 = m1; m1 = c; j1 = 1 + lane + (k << 6); }
        else if (c < m2) m2 = c;
      }
#pragma unroll
      for (int k = 8; k < KPL; ++k) {
        const float c = rc[k] - v[k];
        if (c < n1) { n2 = n1; n1 = c; i1 = 1 + lane + (k << 6); }
        else if (c < n2) n2 = c;
      }
      if (n1 < m1) { m2 = fminf(m1, n2); m1 = n1; j1 = i1; }
      else m2 = fminf(m2, n1);
      for (int m = 1; m < 64; m <<= 1) {
        const float o1 = __shfl_xor(m1, m);
        const float o2 = __shfl_xor(m2, m);
        const int oj = __shfl_xor(j1, m);
        if (o1 < m1) { m2 = fminf(m1, o2); m1 = o1; j1 = oj; }
        else m2 = fminf(m2, o1);
      }
      float d = m2 - m1;
      if (d < 0.f) d = 0.f;
      const int c0 = j1 - 1;
      if ((c0 & 63) == lane) {   // strict decrease of the claimed column's dual
        const int kk = c0 >> 6;
        const float ov = v[kk];
        float nv = ov - d;
        if (!(nv < ov)) nv = nextafterf(ov, -3e38f);
        v[kk] = nv;
      }
      const int k0 = p[j1];      // broadcast LDS read
      p[j1] = i;                 // same-addr write, one lane wins
      if (k0 > 0) {
        if (lane == 0) queue[tail & QMASK] = k0;
        tail++;
      }
      cur = -1;
      if (head < tail) {         // prefetch next pop (FIFO order known)
        cur = queue[head & QMASK];
        const float* Cr = Cb + (size_t)(cur - 1) * STRIDE + lane;
#pragma unroll
        for (int k = 0; k < KPL; ++k) rc[k] = Cr[k << 6];
      }
      rounds++;
    }
    // cap leftovers stay unmatched: graceful tiny loss shift (expected: never)
  }
  __syncthreads();

  // ---- Phase E: fused loss over this batch's 900 queries (512 threads) ----
  double wnll = 0.0, wt = 0.0, l1d = 0.0, gld = 0.0;
  int nm = 0;
  for (int q = tid; q < QQ; q += NT) {
    const int idx = b * QQ + q;
    const float* lg = logits + (size_t)idx * CP1;
    float l[CP1];
    float mx = -1e30f;
    for (int c = 0; c < CP1; ++c) { l[c] = lg[c]; mx = fmaxf(mx, l[c]); }
    float se = 0.f;
    for (int c = 0; c < CP1; ++c) se += expf(l[c] - mx);
    const float lse = logf(se);
    const int g = p[q + 1] - 1;   // row -> gt index (valid gts are a prefix)
    const int t = (g >= 0) ? s_gc[g] : NCLS;
    float lt = l[0];
    for (int c = 1; c < CP1; ++c) lt = (c == t) ? l[c] : lt;
    const float logp = (lt - mx) - lse;
    const float wgt = (t == NCLS) ? 0.1f : 1.0f;
    wnll += (double)(wgt * (-logp));
    wt += (double)wgt;
    if (g >= 0) {
      nm += 1;
      const float* pb = pboxes + (size_t)idx * 4;
      const float* gb = gboxes + ((size_t)b * GG + g) * 4;
      const float pcx = pb[0], pcy = pb[1], pw = pb[2], ph = pb[3];
      const float gcx = gb[0], gcy = gb[1], gw = gb[2], gh = gb[3];
      const float l1 = fabsf(pcx - gcx) + fabsf(pcy - gcy) + fabsf(pw - gw) + fabsf(ph - gh);
      const float px1 = pcx - 0.5f * pw, py1 = pcy - 0.5f * ph;
      const float px2 = pcx + 0.5f * pw, py2 = pcy + 0.5f * ph;
      const float gx1 = gcx - 0.5f * gw, gy1 = gcy - 0.5f * gh;
      const float gx2 = gcx + 0.5f * gw, gy2 = gcy + 0.5f * gh;
      const float pa = fmaxf(px2 - px1, 0.f) * fmaxf(py2 - py1, 0.f);
      const float ga = fmaxf(gx2 - gx1, 0.f) * fmaxf(gy2 - gy1, 0.f);
      const float ltx = fmaxf(px1, gx1), lty = fmaxf(py1, gy1);
      const float rbx = fminf(px2, gx2), rby = fminf(py2, gy2);
      const float iw = fmaxf(rbx - ltx, 0.f), ih = fmaxf(rby - lty, 0.f);
      const float inter = iw * ih;
      const float uni = pa + ga - inter;
      const float iou = inter / fmaxf(uni, 1e-6f);
      const float ex1 = fminf(px1, gx1), ey1 = fminf(py1, gy1);
      const float ex2 = fmaxf(px2, gx2), ey2 = fmaxf(py2, gy2);
      const float ew = fmaxf(ex2 - ex1, 0.f), eh = fmaxf(ey2 - ey1, 0.f);
      const float enc = ew * eh;
      const float giou = iou - (enc - uni) / fmaxf(enc, 1e-6f);
      l1d += (double)l1;
      gld += (double)(1.0f - giou);
    }
  }

  for (int off = 32; off; off >>= 1) {
    wnll += __shfl_down(wnll, off);
    wt   += __shfl_down(wt, off);
    l1d  += __shfl_down(l1d, off);
    gld  += __shfl_down(gld, off);
    nm   += __shfl_down(nm, off);
  }
  if (lane == 0) { r0[w] = wnll; r1[w] = wt; r2[w] = l1d; r3[w] = gld; r4[w] = nm; }
  __syncthreads();
  if (tid == 0) {
    for (int x = 1; x < NW; ++x) { wnll += r0[x]; wt += r1[x]; l1d += r2[x]; gld += r3[x]; nm += r4[x]; }
    atomicAdd(&acc->wnll, wnll);
    atomicAdd(&acc->wt, wt);
    atomicAdd(&acc->l1, l1d);
    atomicAdd(&acc->gl, gld);
    atomicAdd(&acc->nm, nm);
    __threadfence();
    const int ticket = atomicAdd(&acc->counter, 1);
    if (ticket == BB - 1) {
      const double fw = atomicAdd(&acc->wnll, 0.0);
      const double fwt = atomicAdd(&acc->wt, 0.0);
      const double fl1 = atomicAdd(&acc->l1, 0.0);
      const double fgl = atomicAdd(&acc->gl, 0.0);
      int fnm = atomicAdd(&acc->nm, 0);
      if (fnm < 1) fnm = 1;
      const double loss = (double)CLS_W * (fw / fwt) +
                          ((double)L1_W * fl1 + (double)GIOU_W * fgl) / (double)fnm;
      out[0] = (float)loss;
    }
  }
}

extern "C" void kernel_launch(void* const* d_in, const int* in_sizes, int n_in,
                              void* d_out, int out_size, void* d_ws, size_t ws_size,
                              hipStream_t stream) {
  const float* logits = (const float*)d_in[0];
  const float* pboxes = (const float*)d_in[1];
  const int*   gcls   = (const int*)d_in[2];
  const float* gboxes = (const float*)d_in[3];

  char* ws = (char*)d_ws;
  Accum* acc = (Accum*)ws;                 // 64 B, inited in cost_kernel
  float* cost = (float*)(ws + 128);        // B*G*960 floats ~ 24.6 MB

  cost_kernel<<<dim3((STRIDE + 255) / 256, BB), 256, 0, stream>>>(logits, pboxes, gcls, gboxes, cost, acc);
  jv_kernel<<<BB, NT, 0, stream>>>(logits, pboxes, gcls, gboxes, cost, acc, (float*)d_out);
}

// Round 8
// 118.343 us; speedup vs baseline: 1.6134x; 1.0454x over previous
//
#include <hip/hip_runtime.h>
#include <hip/hip_bf16.h>
#include <math.h>

#define BB 64
#define QQ 900
#define GG 100
#define NCLS 10
#define CP1 11

#define STRIDE 960   // 64*15: every lane owns exactly KPL columns; cols 900..959 are +inf pads
#define KPL 15
#define NT 512
#define NW 8
#define QMASK 255    // ring queue; live entries <= n <= 100 < 256
#define ROUND_CAP 20000

#define CLS_W 2.0f
#define L1_W 5.0f
#define GIOU_W 2.0f

struct Accum {
  double wnll, wt, l1, gl;
  int nm, counter;
  int pad[6];
};

// ---------------- cost matrix: cost[b][g][q], 256 blocks (full-chip parallel) ----------------
__global__ __launch_bounds__(256) void cost_kernel(
    const float* __restrict__ logits, const float* __restrict__ pboxes,
    const int* __restrict__ gcls, const float* __restrict__ gboxes,
    float* __restrict__ cost, Accum* acc) {
  const int b = blockIdx.y;
  const int q = blockIdx.x * 256 + threadIdx.x;

  if (blockIdx.x == 0 && blockIdx.y == 0 && threadIdx.x == 0) {
    acc->wnll = 0.0; acc->wt = 0.0; acc->l1 = 0.0; acc->gl = 0.0;
    acc->nm = 0; acc->counter = 0;
  }

  __shared__ float s_gb[GG * 4];
  __shared__ int   s_gc[GG];
  __shared__ float s_prob[256 * 13];

  for (int i = threadIdx.x; i < GG * 4; i += 256) s_gb[i] = gboxes[b * GG * 4 + i];
  for (int i = threadIdx.x; i < GG; i += 256)     s_gc[i] = gcls[b * GG + i];

  float pcx = 0.f, pcy = 0.f, pw = 0.f, ph = 0.f;
  if (q < QQ) {
    const float* lg = logits + ((size_t)b * QQ + q) * CP1;
    float l[CP1];
    float mx = -1e30f;
    for (int c = 0; c < CP1; ++c) { l[c] = lg[c]; mx = fmaxf(mx, l[c]); }
    float se = 0.f;
    for (int c = 0; c < CP1; ++c) { l[c] = expf(l[c] - mx); se += l[c]; }
    float inv = 1.0f / se;
    for (int c = 0; c < CP1; ++c) s_prob[threadIdx.x * 13 + c] = l[c] * inv;
    const float* pb = pboxes + ((size_t)b * QQ + q) * 4;
    pcx = pb[0]; pcy = pb[1]; pw = pb[2]; ph = pb[3];
  }
  __syncthreads();
  if (q >= STRIDE) return;

  float* crow = cost + ((size_t)b * GG) * STRIDE + q;
  if (q >= QQ) {  // pad columns: huge cost, never selected
    for (int g = 0; g < GG; ++g) crow[(size_t)g * STRIDE] = 1e30f;
    return;
  }

  const float px1 = pcx - 0.5f * pw, py1 = pcy - 0.5f * ph;
  const float px2 = pcx + 0.5f * pw, py2 = pcy + 0.5f * ph;
  const float pa = fmaxf(px2 - px1, 0.f) * fmaxf(py2 - py1, 0.f);

  for (int g = 0; g < GG; ++g) {
    int cls = s_gc[g];
    cls = cls < 0 ? 0 : (cls > NCLS - 1 ? NCLS - 1 : cls);
    const float cc = -s_prob[threadIdx.x * 13 + cls];
    const float gcx = s_gb[g * 4 + 0], gcy = s_gb[g * 4 + 1];
    const float gw  = s_gb[g * 4 + 2], gh  = s_gb[g * 4 + 3];
    const float l1 = fabsf(pcx - gcx) + fabsf(pcy - gcy) + fabsf(pw - gw) + fabsf(ph - gh);
    const float gx1 = gcx - 0.5f * gw, gy1 = gcy - 0.5f * gh;
    const float gx2 = gcx + 0.5f * gw, gy2 = gcy + 0.5f * gh;
    const float ga = fmaxf(gx2 - gx1, 0.f) * fmaxf(gy2 - gy1, 0.f);
    const float ltx = fmaxf(px1, gx1), lty = fmaxf(py1, gy1);
    const float rbx = fminf(px2, gx2), rby = fminf(py2, gy2);
    const float iw = fmaxf(rbx - ltx, 0.f), ih = fmaxf(rby - lty, 0.f);
    const float inter = iw * ih;
    const float uni = pa + ga - inter;
    const float iou = inter / fmaxf(uni, 1e-6f);
    const float ex1 = fminf(px1, gx1), ey1 = fminf(py1, gy1);
    const float ex2 = fmaxf(px2, gx2), ey2 = fmaxf(py2, gy2);
    const float ew = fmaxf(ex2 - ex1, 0.f), eh = fmaxf(ey2 - ey1, 0.f);
    const float enc = ew * eh;
    const float giou = iou - (enc - uni) / fmaxf(enc, 1e-6f);
    crow[(size_t)g * STRIDE] = CLS_W * cc + L1_W * l1 - GIOU_W * giou;
  }
}

// ---------------- jv: rowmin + regret-greedy + pipelined single-wave f32 ARR + fused loss ----
__global__ __launch_bounds__(NT) void jv_kernel(
    const float* __restrict__ logits, const float* __restrict__ pboxes,
    const int* __restrict__ gcls, const float* __restrict__ gboxes,
    const float* __restrict__ cost, Accum* acc, float* out) {
  const int b = blockIdx.x;
  const int tid = threadIdx.x;
  const int lane = tid & 63;
  const int w = tid >> 6;

  __shared__ float vl[STRIDE + 2];      // column duals (f32), <= 0
  __shared__ int   p[QQ + 1];           // column -> owning row (1-based), 0 = free
  __shared__ unsigned long long way64[STRIDE + 2];  // regret-max claim keys
  __shared__ float m1l[GG + 1], m2l[GG + 1];
  __shared__ int   aminl[GG + 1];
  __shared__ int   s_gc[GG];
  __shared__ int   queue[QMASK + 1];
  __shared__ int   sh_n, sh_qtail;
  __shared__ double r0[NW], r1[NW], r2[NW], r3[NW];
  __shared__ int r4[NW];

  if (tid == 0) { sh_n = 0; sh_qtail = 0; }
  for (int j = tid; j <= QQ; j += NT) p[j] = 0;
  for (int j = tid; j < STRIDE + 2; j += NT) { vl[j] = 0.f; way64[j] = 0ull; }
  if (tid < GG) s_gc[tid] = gcls[b * GG + tid];
  __syncthreads();
  if (tid < GG && s_gc[tid] >= 0) atomicAdd(&sh_n, 1);
  __syncthreads();
  const int n = sh_n;
  const float* Cb = cost + (size_t)b * GG * STRIDE;

  // ---- Phase B: per-row (min1, min2, argmin), 8 waves in parallel, f32, 2-chain ILP ----
  for (int r = w; r < n; r += NW) {
    const float* Cr = Cb + (size_t)r * STRIDE + lane;
    float rca[KPL];
#pragma unroll
    for (int k = 0; k < KPL; ++k) rca[k] = Cr[k << 6];
    float m1 = 3e38f, m2 = 3e38f, n1 = 3e38f, n2 = 3e38f;
    int j1 = 0x7FFFFFFF, i1 = 0x7FFFFFFF;
#pragma unroll
    for (int k = 0; k < 8; ++k) {
      const float c = rca[k];
      if (c < m1) { m2 = m1; m1 = c; j1 = 1 + lane + (k << 6); }
      else if (c < m2) m2 = c;
    }
#pragma unroll
    for (int k = 8; k < KPL; ++k) {
      const float c = rca[k];
      if (c < n1) { n2 = n1; n1 = c; i1 = 1 + lane + (k << 6); }
      else if (c < n2) n2 = c;
    }
    if (n1 < m1) { m2 = fminf(m1, n2); m1 = n1; j1 = i1; }
    else m2 = fminf(m2, n1);
    for (int m = 1; m < 64; m <<= 1) {
      const float o1 = __shfl_xor(m1, m);
      const float o2 = __shfl_xor(m2, m);
      const int oj = __shfl_xor(j1, m);
      if (o1 < m1) { m2 = fminf(m1, o2); m1 = o1; j1 = oj; }
      else m2 = fminf(m2, o1);
    }
    if (lane == 0) { m1l[r] = m1; m2l[r] = m2; aminl[r] = j1; }
  }
  __syncthreads();

  // ---- Phase C: greedy claim, contested columns go to max regret (fewer cascades) ----
  if (tid < n) {
    const float regret = m2l[tid] - m1l[tid];   // >= 0: non-neg f32 bits are monotone
    const unsigned long long key =
        ((unsigned long long)__float_as_uint(regret) << 20) | (unsigned long long)(tid + 1);
    atomicMax(&way64[aminl[tid]], key);
  }
  __syncthreads();
  if (tid < n) {
    const int j1 = aminl[tid];
    if ((int)(way64[j1] & 0xFFFFFu) == tid + 1) {  // winner: u=m2, vl[j1] = m1 - m2 (<= 0)
      p[j1] = tid + 1;
      vl[j1] = m1l[tid] - m2l[tid];
    } else {                                       // loser: u=m1 stays feasible; queue for ARR
      const int t0 = atomicAdd(&sh_qtail, 1);
      queue[t0 & QMASK] = tid + 1;
    }
  }
  __syncthreads();

  // ---- Phase D: single-wave ARR, register duals, 3-deep row prefetch pipeline ----
  if (w == 0) {
    float v[KPL];
#pragma unroll
    for (int k = 0; k < KPL; ++k) v[k] = vl[1 + lane + (k << 6)];
    int head = 0, tail = sh_qtail, rounds = 0;

    float bufA[KPL], bufB[KPL], bufC[KPL];
    int ia = -1, ib = -1, ic = -1;

    auto loadrow = [&](float* buf, int rid) {
      const float* Cr = Cb + (size_t)(rid - 1) * STRIDE + lane;
#pragma unroll
      for (int k = 0; k < KPL; ++k) buf[k] = Cr[k << 6];
    };
    auto do_step = [&](float* rc, int i) {
      // scan 960 reduced costs: two independent chains + merge (ILP)
      float m1 = 3e38f, m2 = 3e38f, n1 = 3e38f, n2 = 3e38f;
      int j1 = 0x7FFFFFFF, i1 = 0x7FFFFFFF;
#pragma unroll
      for (int k = 0; k < 8; ++k) {
        const float c = rc[k] - v[k];
        if (c < m1) { m2 = m1; m1 = c; j1 = 1 + lane + (k << 6); }
        else if (c < m2) m2 = c;
      }
#pragma unroll
      for (int k = 8; k < KPL; ++k) {
        const float c = rc[k] - v[k];
        if (c < n1) { n2 = n1; n1 = c; i1 = 1 + lane + (k << 6); }
        else if (c < n2) n2 = c;
      }
      if (n1 < m1) { m2 = fminf(m1, n2); m1 = n1; j1 = i1; }
      else m2 = fminf(m2, n1);
      for (int m = 1; m < 64; m <<= 1) {
        const float o1 = __shfl_xor(m1, m);
        const float o2 = __shfl_xor(m2, m);
        const int oj = __shfl_xor(j1, m);
        if (o1 < m1) { m2 = fminf(m1, o2); m1 = o1; j1 = oj; }
        else m2 = fminf(m2, o1);
      }
      float d = m2 - m1;
      if (d < 0.f) d = 0.f;
      const int c0 = j1 - 1;
      if ((c0 & 63) == lane) {   // strict decrease of claimed column's dual
        const int kk = c0 >> 6;
        const float ov = v[kk];
        float nv = ov - d;
        if (!(nv < ov)) nv = nextafterf(ov, -3e38f);
        v[kk] = nv;
      }
      const int k0 = p[j1];      // broadcast LDS read
      p[j1] = i;                 // same-addr write, one lane wins
      head++;
      if (k0 > 0) {
        if (lane == 0) queue[tail & QMASK] = k0;
        tail++;
      }
    };

    // prime the pipeline (rows are immutable: any prefetch depth is correct)
    if (head < tail)     { ia = queue[head & QMASK];       loadrow(bufA, ia); }
    if (head + 1 < tail) { ib = queue[(head + 1) & QMASK]; loadrow(bufB, ib); }
    if (head + 2 < tail) { ic = queue[(head + 2) & QMASK]; loadrow(bufC, ic); }

    while (head < tail && rounds < ROUND_CAP) {
      // step A
      if (ia < 0) { ia = queue[head & QMASK]; loadrow(bufA, ia); }
      do_step(bufA, ia);
      ia = -1;
      if (head + 2 < tail) { ia = queue[(head + 2) & QMASK]; loadrow(bufA, ia); }
      rounds++;
      if (!(head < tail && rounds < ROUND_CAP)) break;
      // step B
      if (ib < 0) { ib = queue[head & QMASK]; loadrow(bufB, ib); }
      do_step(bufB, ib);
      ib = -1;
      if (head + 2 < tail) { ib = queue[(head + 2) & QMASK]; loadrow(bufB, ib); }
      rounds++;
      if (!(head < tail && rounds < ROUND_CAP)) break;
      // step C
      if (ic < 0) { ic = queue[head & QMASK]; loadrow(bufC, ic); }
      do_step(bufC, ic);
      ic = -1;
      if (head + 2 < tail) { ic = queue[(head + 2) & QMASK]; loadrow(bufC, ic); }
      rounds++;
    }
    // cap leftovers stay unmatched: graceful tiny loss shift (expected: never)
  }
  __syncthreads();

  // ---- Phase E: fused loss over this batch's 900 queries (512 threads) ----
  double wnll = 0.0, wt = 0.0, l1d = 0.0, gld = 0.0;
  int nm = 0;
  for (int q = tid; q < QQ; q += NT) {
    const int idx = b * QQ + q;
    const float* lg = logits + (size_t)idx * CP1;
    float l[CP1];
    float mx = -1e30f;
    for (int c = 0; c < CP1; ++c) { l[c] = lg[c]; mx = fmaxf(mx, l[c]); }
    float se = 0.f;
    for (int c = 0; c < CP1; ++c) se += expf(l[c] - mx);
    const float lse = logf(se);
    const int g = p[q + 1] - 1;   // row -> gt index (valid gts are a prefix)
    const int t = (g >= 0) ? s_gc[g] : NCLS;
    float lt = l[0];
    for (int c = 1; c < CP1; ++c) lt = (c == t) ? l[c] : lt;
    const float logp = (lt - mx) - lse;
    const float wgt = (t == NCLS) ? 0.1f : 1.0f;
    wnll += (double)(wgt * (-logp));
    wt += (double)wgt;
    if (g >= 0) {
      nm += 1;
      const float* pb = pboxes + (size_t)idx * 4;
      const float* gb = gboxes + ((size_t)b * GG + g) * 4;
      const float pcx = pb[0], pcy = pb[1], pw = pb[2], ph = pb[3];
      const float gcx = gb[0], gcy = gb[1], gw = gb[2], gh = gb[3];
      const float l1 = fabsf(pcx - gcx) + fabsf(pcy - gcy) + fabsf(pw - gw) + fabsf(ph - gh);
      const float px1 = pcx - 0.5f * pw, py1 = pcy - 0.5f * ph;
      const float px2 = pcx + 0.5f * pw, py2 = pcy + 0.5f * ph;
      const float gx1 = gcx - 0.5f * gw, gy1 = gcy - 0.5f * gh;
      const float gx2 = gcx + 0.5f * gw, gy2 = gcy + 0.5f * gh;
      const float pa = fmaxf(px2 - px1, 0.f) * fmaxf(py2 - py1, 0.f);
      const float ga = fmaxf(gx2 - gx1, 0.f) * fmaxf(gy2 - gy1, 0.f);
      const float ltx = fmaxf(px1, gx1), lty = fmaxf(py1, gy1);
      const float rbx = fminf(px2, gx2), rby = fminf(py2, gy2);
      const float iw = fmaxf(rbx - ltx, 0.f), ih = fmaxf(rby - lty, 0.f);
      const float inter = iw * ih;
      const float uni = pa + ga - inter;
      const float iou = inter / fmaxf(uni, 1e-6f);
      const float ex1 = fminf(px1, gx1), ey1 = fminf(py1, gy1);
      const float ex2 = fmaxf(px2, gx2), ey2 = fmaxf(py2, gy2);
      const float ew = fmaxf(ex2 - ex1, 0.f), eh = fmaxf(ey2 - ey1, 0.f);
      const float enc = ew * eh;
      const float giou = iou - (enc - uni) / fmaxf(enc, 1e-6f);
      l1d += (double)l1;
      gld += (double)(1.0f - giou);
    }
  }

  for (int off = 32; off; off >>= 1) {
    wnll += __shfl_down(wnll, off);
    wt   += __shfl_down(wt, off);
    l1d  += __shfl_down(l1d, off);
    gld  += __shfl_down(gld, off);
    nm   += __shfl_down(nm, off);
  }
  if (lane == 0) { r0[w] = wnll; r1[w] = wt; r2[w] = l1d; r3[w] = gld; r4[w] = nm; }
  __syncthreads();
  if (tid == 0) {
    for (int x = 1; x < NW; ++x) { wnll += r0[x]; wt += r1[x]; l1d += r2[x]; gld += r3[x]; nm += r4[x]; }
    atomicAdd(&acc->wnll, wnll);
    atomicAdd(&acc->wt, wt);
    atomicAdd(&acc->l1, l1d);
    atomicAdd(&acc->gl, gld);
    atomicAdd(&acc->nm, nm);
    __threadfence();
    const int ticket = atomicAdd(&acc->counter, 1);
    if (ticket == BB - 1) {
      const double fw = atomicAdd(&acc->wnll, 0.0);
      const double fwt = atomicAdd(&acc->wt, 0.0);
      const double fl1 = atomicAdd(&acc->l1, 0.0);
      const double fgl = atomicAdd(&acc->gl, 0.0);
      int fnm = atomicAdd(&acc->nm, 0);
      if (fnm < 1) fnm = 1;
      const double loss = (double)CLS_W * (fw / fwt) +
                          ((double)L1_W * fl1 + (double)GIOU_W * fgl) / (double)fnm;
      out[0] = (float)loss;
    }
  }
}

extern "C" void kernel_launch(void* const* d_in, const int* in_sizes, int n_in,
                              void* d_out, int out_size, void* d_ws, size_t ws_size,
                              hipStream_t stream) {
  const float* logits = (const float*)d_in[0];
  const float* pboxes = (const float*)d_in[1];
  const int*   gcls   = (const int*)d_in[2];
  const float* gboxes = (const float*)d_in[3];

  char* ws = (char*)d_ws;
  Accum* acc = (Accum*)ws;                 // 64 B, inited in cost_kernel
  float* cost = (float*)(ws + 128);        // B*G*960 floats ~ 24.6 MB

  cost_kernel<<<dim3((STRIDE + 255) / 256, BB), 256, 0, stream>>>(logits, pboxes, gcls, gboxes, cost, acc);
  jv_kernel<<<BB, NT, 0, stream>>>(logits, pboxes, gcls, gboxes, cost, acc, (float*)d_out);
}